// Round 19
// baseline (188.883 us; speedup 1.0000x reference)
//
#include <hip/hip_runtime.h>
#include <stdint.h>

// Problem constants
#define BB 16
#define TT 4096
#define HH 64
#define MM 640    // HH*DD

#define PADF4 41          // LDS row stride in float4 (656 B)
#define WROWS 8           // t-rows per wave tile
#define NITER 4           // tiles per wave (prefetch hides 3 of 4)

// ---------------------------------------------------------------------------
// Kernel 1: ksum[b][m] = sum_t key[b][t][m]  (~27-30 us, near read roofline)
// ---------------------------------------------------------------------------
__global__ void __launch_bounds__(256)
ksum_kernel(const float* __restrict__ key, float* __restrict__ ksum) {
    int g = blockIdx.x * blockDim.x + threadIdx.x;   // b*160 + c
    int b = g / 160;
    int c = g % 160;
    int t0 = blockIdx.y * 32;

    const float4* p = reinterpret_cast<const float4*>(key)
                    + (size_t)b * TT * 160 + (size_t)t0 * 160 + c;

    float4 a0 = make_float4(0.f,0.f,0.f,0.f);
    float4 a1 = make_float4(0.f,0.f,0.f,0.f);
    float4 a2 = make_float4(0.f,0.f,0.f,0.f);
    float4 a3 = make_float4(0.f,0.f,0.f,0.f);
    #pragma unroll
    for (int i = 0; i < 32; i += 4) {
        float4 x0 = p[(size_t)(i + 0) * 160];
        float4 x1 = p[(size_t)(i + 1) * 160];
        float4 x2 = p[(size_t)(i + 2) * 160];
        float4 x3 = p[(size_t)(i + 3) * 160];
        a0.x += x0.x; a0.y += x0.y; a0.z += x0.z; a0.w += x0.w;
        a1.x += x1.x; a1.y += x1.y; a1.z += x1.z; a1.w += x1.w;
        a2.x += x2.x; a2.y += x2.y; a2.z += x2.z; a2.w += x2.w;
        a3.x += x3.x; a3.y += x3.y; a3.z += x3.z; a3.w += x3.w;
    }
    float sx = (a0.x + a1.x) + (a2.x + a3.x);
    float sy = (a0.y + a1.y) + (a2.y + a3.y);
    float sz = (a0.z + a1.z) + (a2.z + a3.z);
    float sw = (a0.w + a1.w) + (a2.w + a3.w);

    float* dst = ksum + b * MM + c * 4;
    atomicAdd(dst + 0, sx);
    atomicAdd(dst + 1, sy);
    atomicAdd(dst + 2, sz);
    atomicAdd(dst + 3, sw);
}

// ---------------------------------------------------------------------------
// Robust tanh via rcp (exp of negative arg only -> never overflows)
// ---------------------------------------------------------------------------
__device__ __forceinline__ float tanh_rcp(float x) {
    float ax = fabsf(x);
    float e2 = __expf(-2.0f * ax);
    float th = (1.0f - e2) * __builtin_amdgcn_rcpf(1.0f + e2);
    return copysignf(th, x);
}

// ---------------------------------------------------------------------------
// Kernel 2: ZERO-barrier wave-private pipeline.
//   Each wave: own 8-row LDS region + own ksum stage + own t-range ->
//   no cross-wave deps, no __syncthreads, no vmcnt(0) drain ever.
//   Per iteration: issue next tile's 10 coalesced f4 loads; sched_barrier(0)
//   anchor (R13 proved this holds loads in place); compute current tile from
//   LDS; sched_barrier(0); ds_write next tile (compiler inserts COUNTED
//   vmcnt -- latency was hidden under ~1400cy of compute).
//   Same-wave DS ordering is hardware-in-order: RAW/WAR safe w/o waits.
//   VGPR kept flat: no output accumulation, unroll 1 on the tile loop.
// ---------------------------------------------------------------------------
__global__ void __launch_bounds__(256)
attn_kernel(const float* __restrict__ q,
            const float* __restrict__ v,
            const float* __restrict__ ksum,
            float* __restrict__ out) {
    __shared__ float4 qs4[4 * WROWS * PADF4];   // 4 wave regions, 20992 B
    __shared__ float4 vs4[4 * WROWS * PADF4];   // 20992 B
    __shared__ float4 ks4[4 * 40];              // 2560 B  (44.5 KB -> 3/CU)

    const int tid  = threadIdx.x;
    const int w    = tid >> 6;
    const int lane = tid & 63;
    const int bid  = blockIdx.x;                // 0..2047
    const int chunk = bid & 31;                 // 32 chunks of 128 t-rows
    const int hg    = (bid >> 5) & 3;
    const int b     = bid >> 7;

    // ---- wave-private ksum stage (no cross-wave dep) ----
    if (lane < 40) {
        ks4[w * 40 + lane] =
            reinterpret_cast<const float4*>(ksum + b * MM + hg * 160)[lane];
    }

    const int row   = lane & 7;                 // 0..7
    const int head0 = lane >> 3;                // 0..7 (second head = +8)

    const float* ksw = reinterpret_cast<const float*>(&ks4[w * 40]);
    const float R = 0.316227766016838f;         // 1/sqrt(10)
    float ksr0[10], ksr1[10];
    #pragma unroll
    for (int d = 0; d < 10; ++d) {
        ksr0[d] = ksw[head0 * 10 + d] * R;      // lgkmcnt inserted by compiler
        ksr1[d] = ksw[(head0 + 8) * 10 + d] * R;
    }

    // staging slot map: 320 f4 = 8 rows x 40 f4, 5 per lane
    int srow[5], scol[5];
    #pragma unroll
    for (int j = 0; j < 5; ++j) {
        int s = lane + 64 * j;
        srow[j] = s / 40;
        scol[j] = s % 40;
    }

    const float4* qg = reinterpret_cast<const float4*>(q)
                     + (size_t)b * TT * 160 + hg * 40;
    const float4* vg = reinterpret_cast<const float4*>(v)
                     + (size_t)b * TT * 160 + hg * 40;

    float4* qw = &qs4[w * (WROWS * PADF4)];
    float4* vw = &vs4[w * (WROWS * PADF4)];
    const float* qwf = reinterpret_cast<const float*>(qw);
    const float* vwf = reinterpret_cast<const float*>(vw);

    const int tw0 = chunk * 128 + w * 32;       // wave's first t-row
    float* ob = out + ((size_t)(b * HH + hg * 16)) * TT;

    float4 rq[5], rv[5];
    // ---- prologue: load + stage tile 0 ----
    {
        const float4* qt = qg + (size_t)tw0 * 160;
        const float4* vt = vg + (size_t)tw0 * 160;
        #pragma unroll
        for (int j = 0; j < 5; ++j) {
            rq[j] = qt[srow[j] * 160 + scol[j]];
            rv[j] = vt[srow[j] * 160 + scol[j]];
        }
        #pragma unroll
        for (int j = 0; j < 5; ++j) {
            qw[srow[j] * PADF4 + scol[j]] = rq[j];
            vw[srow[j] * PADF4 + scol[j]] = rv[j];
        }
    }

    #pragma unroll 1
    for (int it = 0; it < NITER; ++it) {
        const int t0 = tw0 + it * WROWS;

        // ---- prefetch next tile (issue only; flies under compute) ----
        if (it + 1 < NITER) {
            const float4* qt = qg + (size_t)(t0 + WROWS) * 160;
            const float4* vt = vg + (size_t)(t0 + WROWS) * 160;
            #pragma unroll
            for (int j = 0; j < 5; ++j) {
                rq[j] = qt[srow[j] * 160 + scol[j]];
                rv[j] = vt[srow[j] * 160 + scol[j]];
            }
        }
        __builtin_amdgcn_sched_barrier(0);      // loads stay above compute

        // ---- compute current tile from wave-private LDS ----
        #pragma unroll
        for (int o = 0; o < 2; ++o) {
            const int head  = head0 + 8 * o;
            const int fb    = row * (PADF4 * 4) + head * 10;
            const float* kk = o ? ksr1 : ksr0;  // compile-time (o unrolled)
            float sum = 0.f, dot = 0.f;
            #pragma unroll
            for (int d = 0; d < 10; ++d) {
                float e = __expf(tanh_rcp(qwf[fb + d] * kk[d]));
                sum += e;
                dot += e * vwf[fb + d];
            }
            ob[(size_t)head * TT + t0 + row] = dot * __builtin_amdgcn_rcpf(sum);
        }
        __builtin_amdgcn_sched_barrier(0);      // writes stay below compute

        // ---- stage next tile (counted vmcnt; same-wave DS order = safe) ----
        if (it + 1 < NITER) {
            #pragma unroll
            for (int j = 0; j < 5; ++j) {
                qw[srow[j] * PADF4 + scol[j]] = rq[j];
                vw[srow[j] * PADF4 + scol[j]] = rv[j];
            }
        }
    }
}

// ---------------------------------------------------------------------------
extern "C" void kernel_launch(void* const* d_in, const int* in_sizes, int n_in,
                              void* d_out, int out_size, void* d_ws, size_t ws_size,
                              hipStream_t stream) {
    const float* q = (const float*)d_in[0];
    const float* k = (const float*)d_in[1];
    const float* v = (const float*)d_in[2];
    // d_in[3] = W, d_in[4] = b : dead code (softmax over size-1 axis == 1)
    float* out  = (float*)d_out;
    float* ksum = (float*)d_ws;    // B*M floats = 40 KB

    hipMemsetAsync(d_ws, 0, (size_t)BB * MM * sizeof(float), stream);
    ksum_kernel<<<dim3(10, 128), dim3(256), 0, stream>>>(k, ksum);
    // 16 b x 4 hg x 32 chunks = 2048 blocks (4 waves each, wave-private)
    attn_kernel<<<dim3(2048), dim3(256), 0, stream>>>(q, v, ksum, out);
}

// Round 20
// 111.756 us; speedup vs baseline: 1.6901x; 1.6901x over previous
//
#include <hip/hip_runtime.h>
#include <stdint.h>

// Problem constants
#define BB 16
#define TT 4096
#define HH 64
#define MM 640    // HH*DD

#define TROWS 32          // t-rows per attn tile (best of 8/16/32 sweep)
#define PADF4 41          // LDS row stride in float4 (656 B)
#define ROWSF (PADF4 * 4) // 164 floats

// ---------------------------------------------------------------------------
// Kernel 1: ksum[b][m] = sum_t key[b][t][m]  (~28 us, at read roofline)
// ---------------------------------------------------------------------------
__global__ void __launch_bounds__(256)
ksum_kernel(const float* __restrict__ key, float* __restrict__ ksum) {
    int g = blockIdx.x * blockDim.x + threadIdx.x;   // b*160 + c
    int b = g / 160;
    int c = g % 160;
    int t0 = blockIdx.y * 32;

    const float4* p = reinterpret_cast<const float4*>(key)
                    + (size_t)b * TT * 160 + (size_t)t0 * 160 + c;

    float4 a0 = make_float4(0.f,0.f,0.f,0.f);
    float4 a1 = make_float4(0.f,0.f,0.f,0.f);
    float4 a2 = make_float4(0.f,0.f,0.f,0.f);
    float4 a3 = make_float4(0.f,0.f,0.f,0.f);
    #pragma unroll
    for (int i = 0; i < 32; i += 4) {
        float4 x0 = p[(size_t)(i + 0) * 160];
        float4 x1 = p[(size_t)(i + 1) * 160];
        float4 x2 = p[(size_t)(i + 2) * 160];
        float4 x3 = p[(size_t)(i + 3) * 160];
        a0.x += x0.x; a0.y += x0.y; a0.z += x0.z; a0.w += x0.w;
        a1.x += x1.x; a1.y += x1.y; a1.z += x1.z; a1.w += x1.w;
        a2.x += x2.x; a2.y += x2.y; a2.z += x2.z; a2.w += x2.w;
        a3.x += x3.x; a3.y += x3.y; a3.z += x3.z; a3.w += x3.w;
    }
    float sx = (a0.x + a1.x) + (a2.x + a3.x);
    float sy = (a0.y + a1.y) + (a2.y + a3.y);
    float sz = (a0.z + a1.z) + (a2.z + a3.z);
    float sw = (a0.w + a1.w) + (a2.w + a3.w);

    float* dst = ksum + b * MM + c * 4;
    atomicAdd(dst + 0, sx);
    atomicAdd(dst + 1, sy);
    atomicAdd(dst + 2, sz);
    atomicAdd(dst + 3, sw);
}

// ---------------------------------------------------------------------------
// Robust tanh via rcp (exp of negative arg only -> never overflows)
// ---------------------------------------------------------------------------
__device__ __forceinline__ float tanh_rcp(float x) {
    float ax = fabsf(x);
    float e2 = __expf(-2.0f * ax);
    float th = (1.0f - e2) * __builtin_amdgcn_rcpf(1.0f + e2);
    return copysignf(th, x);
}

// ---------------------------------------------------------------------------
// Kernel 2 (CHAMPION, benched 110.96 us total): TROWS=32 / 256 threads.
//   - q/v: 10 coalesced f4/thread -> regs -> LDS (pad 41)
//   - ksum: one f4 instruction (tid<40) -> LDS; broadcast reads
//   - compute: 2 outputs/thread; 128B-segment stores
//   LDS 42.6 KB -> 3 blocks/CU = 12 waves/CU; one vmcnt(0)+barrier per
//   40 KB generation (best drain amortization that keeps >=3 blocks/CU).
// ---------------------------------------------------------------------------
__global__ void __launch_bounds__(256)
attn_kernel(const float* __restrict__ q,
            const float* __restrict__ v,
            const float* __restrict__ ksum,
            float* __restrict__ out) {
    __shared__ float qs[TROWS * ROWSF];   // 20992 B
    __shared__ float vs[TROWS * ROWSF];   // 20992 B
    __shared__ float ks_lds[160];         // 640 B

    const int tid = threadIdx.x;          // 0..255
    const int hg  = blockIdx.x;           // 0..3 (fastest)
    const int t0  = blockIdx.y * TROWS;
    const int b   = blockIdx.z;

    const float4* qg = reinterpret_cast<const float4*>(q)
                     + ((size_t)(b * TT + t0)) * 160 + hg * 40;
    const float4* vg = reinterpret_cast<const float4*>(v)
                     + ((size_t)(b * TT + t0)) * 160 + hg * 40;

    // ---- stage: 5 q-f4 + 5 v-f4 per thread (coalesced, 2KB/instr/wave) ----
    float4 rq[5], rv[5];
    #pragma unroll
    for (int j = 0; j < 5; ++j) {
        int s   = tid + 256 * j;          // 0..1279 (tile = 32 rows x 40 f4)
        int row = s / 40;
        int c   = s % 40;
        rq[j] = qg[(size_t)row * 160 + c];
        rv[j] = vg[(size_t)row * 160 + c];
    }
    if (tid < 40) {
        reinterpret_cast<float4*>(ks_lds)[tid] =
            reinterpret_cast<const float4*>(ksum + b * MM + hg * 160)[tid];
    }

    float4* qs4 = reinterpret_cast<float4*>(qs);
    float4* vs4 = reinterpret_cast<float4*>(vs);
    #pragma unroll
    for (int j = 0; j < 5; ++j) {
        int s   = tid + 256 * j;
        int row = s / 40;
        int c   = s % 40;
        qs4[row * PADF4 + c] = rq[j];
        vs4[row * PADF4 + c] = rv[j];
    }
    __syncthreads();

    // ---- ksum rows from LDS (broadcast within 32-lane groups) ----
    const float R = 0.316227766016838f;   // 1/sqrt(10)
    const int head0 = tid >> 5;           // 0..7 (second head = +8)
    const int row   = tid & 31;

    float ksr0[10], ksr1[10];
    #pragma unroll
    for (int d = 0; d < 10; ++d) {
        ksr0[d] = ks_lds[head0 * 10 + d] * R;
        ksr1[d] = ks_lds[(head0 + 8) * 10 + d] * R;
    }

    // ---- compute: 2 (row, head) outputs per thread ----
    #pragma unroll
    for (int o = 0; o < 2; ++o) {
        const int head  = head0 + o * 8;
        const int lbase = row * ROWSF + head * 10;
        const float* kk = o ? ksr1 : ksr0;
        float sum = 0.f, dot = 0.f;
        #pragma unroll
        for (int d = 0; d < 10; ++d) {
            float e = __expf(tanh_rcp(qs[lbase + d] * kk[d]));
            sum += e;
            dot += e * vs[lbase + d];
        }
        out[((size_t)(b * HH + hg * 16 + head)) * TT + t0 + row]
            = dot * __builtin_amdgcn_rcpf(sum);
    }
}

// ---------------------------------------------------------------------------
extern "C" void kernel_launch(void* const* d_in, const int* in_sizes, int n_in,
                              void* d_out, int out_size, void* d_ws, size_t ws_size,
                              hipStream_t stream) {
    const float* q = (const float*)d_in[0];
    const float* k = (const float*)d_in[1];
    const float* v = (const float*)d_in[2];
    // d_in[3] = W, d_in[4] = b : dead code (softmax over size-1 axis == 1)
    float* out  = (float*)d_out;
    float* ksum = (float*)d_ws;    // B*M floats = 40 KB

    hipMemsetAsync(d_ws, 0, (size_t)BB * MM * sizeof(float), stream);
    ksum_kernel<<<dim3(10, 128), dim3(256), 0, stream>>>(k, ksum);
    // hg fastest, then t (128 tiles of 32 rows), then b
    attn_kernel<<<dim3(4, TT / TROWS, BB), dim3(256), 0, stream>>>(q, v, ksum, out);
}